// Round 15
// baseline (590.976 us; speedup 1.0000x reference)
//
#include <hip/hip_runtime.h>
#include <hip/hip_bf16.h>

typedef __hip_bfloat16 bf16;
typedef __attribute__((ext_vector_type(8))) short bf16x8;  // 8 bf16 in 4 VGPRs
typedef __attribute__((ext_vector_type(4))) float f32x4;

// ---------------- bf16 split helpers (Ootomo bf16x3 scheme) ----------------

__device__ __forceinline__ short f2bf(float x) {  // RNE float->bf16 bits
    unsigned u = __float_as_uint(x);
    unsigned r = (u + 0x7FFFu + ((u >> 16) & 1u)) >> 16;
    return (short)r;
}
__device__ __forceinline__ float bf2f(short s) {
    return __uint_as_float(((unsigned)(unsigned short)s) << 16);
}
__device__ __forceinline__ void split1(float v, short& h, short& l) {  // RNE-RNE
    h = f2bf(v);
    l = f2bf(v - bf2f(h));
}
// Cheap split: RTZ hi (1 shr) + RNE lo. Pair represents v to ~2^-17 rel.
__device__ __forceinline__ void split1_rtz(float v, short& h, short& l) {
    unsigned u = __float_as_uint(v);
    h = (short)(u >> 16);
    float r = v - __uint_as_float(u & 0xFFFF0000u);
    l = f2bf(r);
}

// tanh without clamp: exp saturates (inf -> 1, 0 -> -1). 6 VALU ops.
__device__ __forceinline__ float fast_tanh(float x) {
    float t = __expf(x + x);
    return 1.f - __fdividef(2.f, t + 1.f);
}

__device__ __forceinline__ void fma4(float4& acc, float v, const float4& x) {
    acc.x = fmaf(v, x.x, acc.x);
    acc.y = fmaf(v, x.y, acc.y);
    acc.z = fmaf(v, x.z, acc.z);
    acc.w = fmaf(v, x.w, acc.w);
}

__device__ __forceinline__ void red4(float4& a) {
    a.x += __shfl_xor(a.x, 16); a.y += __shfl_xor(a.y, 16);
    a.z += __shfl_xor(a.z, 16); a.w += __shfl_xor(a.w, 16);
    a.x += __shfl_xor(a.x, 32); a.y += __shfl_xor(a.y, 32);
    a.z += __shfl_xor(a.z, 32); a.w += __shfl_xor(a.w, 32);
}

// ---------------- dtype forensics (masks / indices) ----------------
// modes: 0=u8/bool, 1=int32, 2=float32, 3=int64, 4=float64
__global__ __launch_bounds__(256) void forensic_kernel(const unsigned int* __restrict__ mask_w,
                                                       const unsigned int* __restrict__ idx_w,
                                                       int nw_mask, int nw_idx,
                                                       int* __restrict__ flags) {
    __shared__ int sm[6];
    int t = threadIdx.x;
    if (t < 6) sm[t] = 0;
    __syncthreads();
    int m_gt1 = 0, m_f32 = 0, m_f64 = 0, m_oddnz = 0, i_hi = 0, i_oddnz = 0;
    for (int i = t; i < nw_mask; i += 256) {
        unsigned int w = mask_w[i];
        if (w > 1u && w != 0x3F800000u && w != 0x3FF00000u) m_gt1++;
        if (w == 0x3F800000u) m_f32++;
        if ((i & 1) && w == 0x3FF00000u) m_f64++;
        if ((i & 1) && w != 0u) m_oddnz++;
    }
    for (int i = t; i < nw_idx; i += 256) {
        unsigned int v = idx_w[i];
        if (v >= 0x20000000u) i_hi++;
        if ((i & 1) && v != 0u) i_oddnz++;
    }
    atomicAdd(&sm[0], m_gt1);
    atomicAdd(&sm[1], m_f32);
    atomicAdd(&sm[2], m_f64);
    atomicAdd(&sm[3], m_oddnz);
    atomicAdd(&sm[4], i_hi);
    atomicAdd(&sm[5], i_oddnz);
    __syncthreads();
    if (t == 0) {
        int mmode;
        if (sm[1] > 50) mmode = 2;
        else if (sm[2] > 50) mmode = 4;
        else if (sm[0] > 50) mmode = 0;
        else if (sm[3] > 50) mmode = 1;
        else mmode = 3;
        int imode;
        if (sm[4] > (nw_idx * 3) / 4) imode = 2;
        else if (sm[4] > nw_idx / 4) imode = 4;
        else if (sm[5] > 50) imode = 1;
        else imode = 3;
        flags[0] = mmode;
        flags[1] = imode;
    }
}

__device__ __forceinline__ int fetch_idx(const void* p, int e, int mode) {
    switch (mode) {
        case 1: return ((const int*)p)[e];
        case 3: return (int)(((const long long*)p)[e]);
        case 2: return (int)(((const float*)p)[e]);
        default: return (int)(((const double*)p)[e]);
    }
}

__device__ __forceinline__ bool conv_one(const void* m, int mode, int i) {
    switch (mode) {
        case 0: return ((const unsigned char*)m)[i] != 0;
        case 1: return ((const int*)m)[i] != 0;
        case 2: return ((const float*)m)[i] != 0.f;
        case 3: return ((const long long*)m)[i] != 0;
        default: return ((const double*)m)[i] != 0.0;
    }
}

// Both masks in one launch.
__global__ __launch_bounds__(256) void conv_masks(const void* __restrict__ m1,
                                                  const void* __restrict__ m2,
                                                  const int* __restrict__ flags, int n,
                                                  unsigned char* __restrict__ o1,
                                                  unsigned char* __restrict__ o2) {
    int mode = flags[0];
    int i = blockIdx.x * 256 + threadIdx.x;
    if (i >= n) return;
    o1[i] = conv_one(m1, mode, i) ? 1 : 0;
    o2[i] = conv_one(m2, mode, i) ? 1 : 0;
}

// ---------------- weight pre-split: RNE planes computed ONCE ----------------

__global__ __launch_bounds__(256) void split_weights(const float* __restrict__ W,
                                                     const float* __restrict__ fcw, int wn,
                                                     int fn, short* __restrict__ whi,
                                                     short* __restrict__ wlo,
                                                     short* __restrict__ fhi,
                                                     short* __restrict__ flo) {
    int i = blockIdx.x * 256 + threadIdx.x;
    if (i < wn) {
        short h, l;
        split1(W[i], h, l);
        whi[i] = h;
        wlo[i] = l;
    } else if (i < wn + fn) {
        int j = i - wn;
        short h, l;
        split1(fcw[j], h, l);
        fhi[j] = h;
        flo[j] = l;
    }
}

// ---------------- CSR build: two-level bucket sort, block-aggregated binning --------

__global__ __launch_bounds__(256) void bucket_hist(const void* __restrict__ row,
                                                   const int* __restrict__ flags, int e_cnt,
                                                   int n, int shift, int nb,
                                                   int* __restrict__ bcnt) {
    __shared__ int hist[2048];
    int t = threadIdx.x;
    for (int i = t; i < nb; i += 256) hist[i] = 0;
    __syncthreads();
    int imode = flags[1];
    for (int e = blockIdx.x * 256 + t; e < e_cnt; e += gridDim.x * 256) {
        int r = fetch_idx(row, e, imode);
        if ((unsigned)r < (unsigned)n) atomicAdd(&hist[r >> shift], 1);
    }
    __syncthreads();
    for (int i = t; i < nb; i += 256)
        if (hist[i]) atomicAdd(&bcnt[i], hist[i]);
}

// bptr: in = counts, out = exclusive offsets; also fills bcur and row_ptr[n].
__global__ __launch_bounds__(1024) void bucket_scan(int* __restrict__ bptr, int nb,
                                                    int* __restrict__ bcur, int n,
                                                    int* __restrict__ row_ptr) {
    __shared__ int sh[1024];
    int t = threadIdx.x;
    int i0 = t * 2, i1 = t * 2 + 1;
    int a = (i0 < nb) ? bptr[i0] : 0;
    int b = (i1 < nb) ? bptr[i1] : 0;
    int s = a + b;
    sh[t] = s;
    __syncthreads();
    for (int off = 1; off < 1024; off <<= 1) {
        int u = (t >= off) ? sh[t - off] : 0;
        __syncthreads();
        sh[t] += u;
        __syncthreads();
    }
    int base = sh[t] - s;  // exclusive prefix
    if (i0 < nb) { bptr[i0] = base; bcur[i0] = base; }
    if (i1 < nb) { bptr[i1] = base + a; bcur[i1] = base + a; }
    if (t == 1023) {
        bptr[nb] = sh[1023];
        row_ptr[n] = sh[1023];
    }
}

// Block-aggregated binning; 2048 edges/block, register-cached.
__global__ __launch_bounds__(256) void bin_pass2(const void* __restrict__ row,
                                                 const void* __restrict__ col,
                                                 const float* __restrict__ vals,
                                                 const int* __restrict__ flags, int e_cnt, int n,
                                                 int shift, int nb, int* __restrict__ bcur,
                                                 int2* __restrict__ rcbin,
                                                 float* __restrict__ valbin) {
    __shared__ int hist[2048];
    __shared__ int base[2048];
    int t = threadIdx.x;
    int e0 = blockIdx.x * 2048;
    if (e0 >= e_cnt) return;
    int imode = flags[1];
    for (int i = t; i < nb; i += 256) hist[i] = 0;
    __syncthreads();
    // phase 1: load this thread's 8 edges into registers + LDS histogram
    int rr[8], cc[8];
    float vv[8];
    bool ok[8];
#pragma unroll
    for (int j = 0; j < 8; j++) {
        int e = e0 + j * 256 + t;
        ok[j] = false;
        if (e < e_cnt) {
            int r = fetch_idx(row, e, imode);
            if ((unsigned)r < (unsigned)n) {
                ok[j] = true;
                rr[j] = r;
                int c = fetch_idx(col, e, imode);
                cc[j] = ((unsigned)c < (unsigned)n) ? c : 0;
                vv[j] = vals[e];
                atomicAdd(&hist[r >> shift], 1);
            }
        }
    }
    __syncthreads();
    // phase 2: reserve one contiguous range per bucket (1 global atomic each)
    for (int i = t; i < nb; i += 256) {
        int c = hist[i];
        base[i] = c ? atomicAdd(&bcur[i], c) : 0;
        hist[i] = 0;  // reuse as within-block cursor
    }
    __syncthreads();
    // phase 3: scatter from registers into reserved ranges
#pragma unroll
    for (int j = 0; j < 8; j++) {
        if (ok[j]) {
            int bk = rr[j] >> shift;
            int pos = base[bk] + atomicAdd(&hist[bk], 1);
            rcbin[pos] = make_int2(rr[j], cc[j]);
            valbin[pos] = vv[j];
        }
    }
}

// One block per bucket, 512 threads. rows-per-bucket <= 1024.
__global__ __launch_bounds__(512) void csr_finalize(const int* __restrict__ bptr,
                                                    const int2* __restrict__ rcbin,
                                                    const float* __restrict__ valbin, int n,
                                                    int shift, int* __restrict__ row_ptr,
                                                    int* __restrict__ col_s,
                                                    float* __restrict__ val_s) {
    __shared__ int cnt[1024];
    __shared__ int curs[1024];
    __shared__ int red[512];
    int b = blockIdx.x, t = threadIdx.x;
    int rpb = 1 << shift;
    int r0 = b << shift;
    int rows = n - r0;
    if (rows <= 0) return;
    if (rows > rpb) rows = rpb;
    int ebase = bptr[b], eend = bptr[b + 1];
    for (int i = t; i < rows; i += 512) cnt[i] = 0;
    __syncthreads();
    for (int e = ebase + t; e < eend; e += 512) atomicAdd(&cnt[rcbin[e].x - r0], 1);
    __syncthreads();
    // exclusive scan of cnt[0..rows): 2 values per thread + block scan
    int v[2], s = 0;
#pragma unroll
    for (int j = 0; j < 2; j++) {
        int idx = t * 2 + j;
        v[j] = (idx < rows) ? cnt[idx] : 0;
        s += v[j];
    }
    red[t] = s;
    __syncthreads();
    for (int off = 1; off < 512; off <<= 1) {
        int u = (t >= off) ? red[t - off] : 0;
        __syncthreads();
        red[t] += u;
        __syncthreads();
    }
    int run = ebase + red[t] - s;
#pragma unroll
    for (int j = 0; j < 2; j++) {
        int idx = t * 2 + j;
        if (idx < rows) {
            row_ptr[r0 + idx] = run;
            curs[idx] = run;
            run += v[j];
        }
    }
    __syncthreads();
    for (int e = ebase + t; e < eend; e += 512) {
        int2 rc = rcbin[e];
        float vv = valbin[e];
        int pos = atomicAdd(&curs[rc.x - r0], 1);
        col_s[pos] = rc.y;
        val_s[pos] = vv;
    }
}

// ---------------- SpMM: ax = A @ x  (CSR, one wave per row) ----------------
// One row/wave, 4-deep gather unroll (measured best, rounds 7/9). Mask bit in
// bit 30 of the shfl'd column; masked accumulator = full - masked-only diff.

__device__ __forceinline__ void store_split4(short* __restrict__ hi, short* __restrict__ lo,
                                             size_t o, const float4& v) {
    short4 h4, l4;
    split1(v.x, h4.x, l4.x); split1(v.y, h4.y, l4.y);
    split1(v.z, h4.z, l4.z); split1(v.w, h4.w, l4.w);
    *(short4*)(hi + o) = h4;
    *(short4*)(lo + o) = l4;
}

__global__ __launch_bounds__(256) void spmm_dual(const float* __restrict__ X,
                                                 const int* __restrict__ row_ptr,
                                                 const int* __restrict__ col_s,
                                                 const float* __restrict__ val_s,
                                                 const unsigned char* __restrict__ mask, int n,
                                                 short* __restrict__ axm_hi,
                                                 short* __restrict__ axm_lo,
                                                 short* __restrict__ axf_hi,
                                                 short* __restrict__ axf_lo) {
    int gid = blockIdx.x * 256 + threadIdx.x;
    int r = gid >> 6;
    if (r >= n) return;
    int lane = threadIdx.x & 63;
    int g = lane >> 4, sub = lane & 15;
    int s = row_ptr[r], e = row_ptr[r + 1];
    int cnt = e - s;
    int mycm = 0;  // col | (mask<<30)
    float myv = 0.f;
    if (lane < cnt) {
        int c = col_s[s + lane];
        myv = val_s[s + lane];
        mycm = c | (mask[c] ? (1 << 30) : 0);
    }
    int cmain = cnt > 64 ? 64 : cnt;
    float4 fA = {0, 0, 0, 0}, fB = {0, 0, 0, 0};  // full sums
    float4 dA = {0, 0, 0, 0}, dB = {0, 0, 0, 0};  // masked-edge sums
    for (int i = 0; i < cmain; i += 16) {
        int i0 = i + g, i1 = i + 4 + g, i2 = i + 8 + g, i3 = i + 12 + g;
        int c0 = __shfl(mycm, i0), c1 = __shfl(mycm, i1);
        int c2 = __shfl(mycm, i2), c3 = __shfl(mycm, i3);
        float v0 = __shfl(myv, i0), v1 = __shfl(myv, i1);
        float v2 = __shfl(myv, i2), v3 = __shfl(myv, i3);
        if (i0 < cmain) {
            float4 x = *(const float4*)(X + (size_t)(c0 & 0x3FFFFFFF) * 64 + sub * 4);
            fma4(fA, v0, x);
            if (c0 >> 30) fma4(dA, v0, x);
        }
        if (i1 < cmain) {
            float4 x = *(const float4*)(X + (size_t)(c1 & 0x3FFFFFFF) * 64 + sub * 4);
            fma4(fB, v1, x);
            if (c1 >> 30) fma4(dB, v1, x);
        }
        if (i2 < cmain) {
            float4 x = *(const float4*)(X + (size_t)(c2 & 0x3FFFFFFF) * 64 + sub * 4);
            fma4(fA, v2, x);
            if (c2 >> 30) fma4(dA, v2, x);
        }
        if (i3 < cmain) {
            float4 x = *(const float4*)(X + (size_t)(c3 & 0x3FFFFFFF) * 64 + sub * 4);
            fma4(fB, v3, x);
            if (c3 >> 30) fma4(dB, v3, x);
        }
    }
    for (int i = 64 + g; i < cnt; i += 4) {  // rare overflow rows
        int c = col_s[s + i];
        float v = val_s[s + i];
        float4 x = *(const float4*)(X + (size_t)c * 64 + sub * 4);
        fma4(fA, v, x);
        if (mask[c]) fma4(dA, v, x);
    }
    fA.x += fB.x; fA.y += fB.y; fA.z += fB.z; fA.w += fB.w;
    dA.x += dB.x; dA.y += dB.y; dA.z += dB.z; dA.w += dB.w;
    red4(fA);
    red4(dA);
    if (g == 0) {
        float4 mA = make_float4(fA.x - dA.x, fA.y - dA.y, fA.z - dA.z, fA.w - dA.w);
        size_t o = (size_t)r * 64 + sub * 4;
        store_split4(axf_hi, axf_lo, o, fA);
        store_split4(axm_hi, axm_lo, o, mA);
    }
}

// Single-output masked SpMM; masked edges skip the gather entirely.
__global__ __launch_bounds__(256) void spmm_one(const float* __restrict__ X,
                                                const int* __restrict__ row_ptr,
                                                const int* __restrict__ col_s,
                                                const float* __restrict__ val_s,
                                                const unsigned char* __restrict__ mask, int n,
                                                short* __restrict__ ax_hi,
                                                short* __restrict__ ax_lo) {
    int gid = blockIdx.x * 256 + threadIdx.x;
    int r = gid >> 6;
    if (r >= n) return;
    int lane = threadIdx.x & 63;
    int g = lane >> 4, sub = lane & 15;
    int s = row_ptr[r], e = row_ptr[r + 1];
    int cnt = e - s;
    int myc = 0;
    float myv = 0.f;
    if (lane < cnt) {
        myc = col_s[s + lane];
        float v = val_s[s + lane];
        myv = mask[myc] ? 0.f : v;
    }
    int cmain = cnt > 64 ? 64 : cnt;
    float4 aA = {0, 0, 0, 0}, aB = {0, 0, 0, 0};
    for (int i = 0; i < cmain; i += 16) {
        int i0 = i + g, i1 = i + 4 + g, i2 = i + 8 + g, i3 = i + 12 + g;
        int c0 = __shfl(myc, i0), c1 = __shfl(myc, i1);
        int c2 = __shfl(myc, i2), c3 = __shfl(myc, i3);
        float v0 = __shfl(myv, i0), v1 = __shfl(myv, i1);
        float v2 = __shfl(myv, i2), v3 = __shfl(myv, i3);
        if (i0 < cmain && v0 != 0.f) {
            float4 x = *(const float4*)(X + (size_t)c0 * 64 + sub * 4);
            fma4(aA, v0, x);
        }
        if (i1 < cmain && v1 != 0.f) {
            float4 x = *(const float4*)(X + (size_t)c1 * 64 + sub * 4);
            fma4(aB, v1, x);
        }
        if (i2 < cmain && v2 != 0.f) {
            float4 x = *(const float4*)(X + (size_t)c2 * 64 + sub * 4);
            fma4(aA, v2, x);
        }
        if (i3 < cmain && v3 != 0.f) {
            float4 x = *(const float4*)(X + (size_t)c3 * 64 + sub * 4);
            fma4(aB, v3, x);
        }
    }
    for (int i = 64 + g; i < cnt; i += 4) {
        int c = col_s[s + i];
        if (mask[c]) continue;
        float v = val_s[s + i];
        float4 x = *(const float4*)(X + (size_t)c * 64 + sub * 4);
        fma4(aA, v, x);
    }
    aA.x += aB.x; aA.y += aB.y; aA.z += aB.z; aA.w += aB.w;
    red4(aA);
    if (g == 0) {
        size_t o = (size_t)r * 64 + sub * 4;
        store_split4(ax_hi, ax_lo, o, aA);
    }
}

// ---------------- fused kernel A: embed GEMM -> LDS bf16 planes -> fc GEMM -> tanh-sum ----
// Round-15: partials stored BLOCK-MAJOR (s_part[block*512+val] -- each wave's
// q==0 lanes write 64B contiguous, no line amplification; round-14's transposed
// layout caused 24MB of 64B-line allocations). reduce_ssums is parallel over
// values with strided reads (8.4MB total, L2-resident).

template <int PP>
__global__ __launch_bounds__(256) void gemm_tanh(const short* __restrict__ Xhi0,
                                                 const short* __restrict__ Xlo0,
                                                 const short* __restrict__ Xhi1,
                                                 const short* __restrict__ Xlo1,
                                                 const short* __restrict__ Whi_g,
                                                 const short* __restrict__ Wlo_g,
                                                 const float* __restrict__ b,
                                                 const float* __restrict__ a,
                                                 const short* __restrict__ fchi_g,
                                                 const short* __restrict__ fclo_g,
                                                 const float* __restrict__ fcb, int n, int ntiles,
                                                 float* __restrict__ s_sums,
                                                 float* __restrict__ s_part) {
    __shared__ __align__(16) short ehi[PP][16][72], elo[PP][16][72];
    int set = blockIdx.y;
    const short* __restrict__ Xhi = set ? Xhi1 : Xhi0;
    const short* __restrict__ Xlo = set ? Xlo1 : Xlo0;
    int t = threadIdx.x;
    int wv = t >> 6, lane = t & 63, nl = lane & 15, q = lane >> 4;
    int colg = wv * 16 + nl;
    bf16x8 whi[PP][2], wlo[PP][2];
    float bias[PP], slope[PP];
#pragma unroll
    for (int p = 0; p < PP; p++) {
#pragma unroll
        for (int kk = 0; kk < 2; kk++) {
            whi[p][kk] = *(const bf16x8*)(Whi_g + p * 4096 + colg * 64 + kk * 32 + q * 8);
            wlo[p][kk] = *(const bf16x8*)(Wlo_g + p * 4096 + colg * 64 + kk * 32 + q * 8);
        }
        bias[p] = b[p * 64 + colg];
        slope[p] = a[p];
    }
    bf16x8 fhi[2], flo[2];
#pragma unroll
    for (int kk = 0; kk < 2; kk++) {
        fhi[kk] = *(const bf16x8*)(fchi_g + colg * 64 + kk * 32 + q * 8);
        flo[kk] = *(const bf16x8*)(fclo_g + colg * 64 + kk * 32 + q * 8);
    }
    float fbias = fcb[colg];
    float ssum[PP];
#pragma unroll
    for (int p = 0; p < PP; p++) ssum[p] = 0.f;

    int rt = blockIdx.x;
    bf16x8 ah[2], al[2];
    if (rt < ntiles) {
        size_t rb = (size_t)(rt * 16 + nl) * 64 + q * 8;
#pragma unroll
        for (int kk = 0; kk < 2; kk++) {
            ah[kk] = *(const bf16x8*)(Xhi + rb + kk * 32);
            al[kk] = *(const bf16x8*)(Xlo + rb + kk * 32);
        }
    }
    for (; rt < ntiles; rt += gridDim.x) {
#pragma unroll
        for (int p = 0; p < PP; p++) {
            f32x4 acc = {0.f, 0.f, 0.f, 0.f};
            acc = __builtin_amdgcn_mfma_f32_16x16x32_bf16(ah[0], whi[p][0], acc, 0, 0, 0);
            acc = __builtin_amdgcn_mfma_f32_16x16x32_bf16(ah[1], whi[p][1], acc, 0, 0, 0);
            acc = __builtin_amdgcn_mfma_f32_16x16x32_bf16(al[0], whi[p][0], acc, 0, 0, 0);
            acc = __builtin_amdgcn_mfma_f32_16x16x32_bf16(al[1], whi[p][1], acc, 0, 0, 0);
            acc = __builtin_amdgcn_mfma_f32_16x16x32_bf16(ah[0], wlo[p][0], acc, 0, 0, 0);
            acc = __builtin_amdgcn_mfma_f32_16x16x32_bf16(ah[1], wlo[p][1], acc, 0, 0, 0);
            acc = __builtin_amdgcn_mfma_f32_16x16x32_bf16(al[0], wlo[p][0], acc, 0, 0, 0);
            acc = __builtin_amdgcn_mfma_f32_16x16x32_bf16(al[1], wlo[p][1], acc, 0, 0, 0);
#pragma unroll
            for (int i = 0; i < 4; i++) {
                float o = acc[i] + bias[p];
                o = (o > 0.f) ? o : slope[p] * o;
                short hb, lb;
                split1_rtz(o, hb, lb);
                ehi[p][q * 4 + i][colg] = hb;
                elo[p][q * 4 + i][colg] = lb;
            }
        }
        // prefetch next tile's A-fragments (overlaps the fc phase below)
        int rn = rt + gridDim.x;
        bf16x8 pfh[2], pfl[2];
        if (rn < ntiles) {
            size_t rb = (size_t)(rn * 16 + nl) * 64 + q * 8;
#pragma unroll
            for (int kk = 0; kk < 2; kk++) {
                pfh[kk] = *(const bf16x8*)(Xhi + rb + kk * 32);
                pfl[kk] = *(const bf16x8*)(Xlo + rb + kk * 32);
            }
        }
        __syncthreads();
#pragma unroll
        for (int p = 0; p < PP; p++) {
            bf16x8 eh[2], el[2];
#pragma unroll
            for (int kk = 0; kk < 2; kk++) {
                eh[kk] = *(const bf16x8*)(&ehi[p][nl][kk * 32 + q * 8]);
                el[kk] = *(const bf16x8*)(&elo[p][nl][kk * 32 + q * 8]);
            }
            f32x4 acc = {0.f, 0.f, 0.f, 0.f};
            acc = __builtin_amdgcn_mfma_f32_16x16x32_bf16(eh[0], fhi[0], acc, 0, 0, 0);
            acc = __builtin_amdgcn_mfma_f32_16x16x32_bf16(eh[1], fhi[1], acc, 0, 0, 0);
            acc = __builtin_amdgcn_mfma_f32_16x16x32_bf16(el[0], fhi[0], acc, 0, 0, 0);
            acc = __builtin_amdgcn_mfma_f32_16x16x32_bf16(el[1], fhi[1], acc, 0, 0, 0);
            acc = __builtin_amdgcn_mfma_f32_16x16x32_bf16(eh[0], flo[0], acc, 0, 0, 0);
            acc = __builtin_amdgcn_mfma_f32_16x16x32_bf16(eh[1], flo[1], acc, 0, 0, 0);
#pragma unroll
            for (int i = 0; i < 4; i++) {
                int r = rt * 16 + q * 4 + i;
                if (r < n) ssum[p] += fast_tanh(acc[i] + fbias);
            }
        }
        __syncthreads();  // LDS reads done before next tile's writes
#pragma unroll
        for (int kk = 0; kk < 2; kk++) {
            ah[kk] = pfh[kk];
            al[kk] = pfl[kk];
        }
    }
    if (s_part != nullptr) {
        // block-major: s_part[(set*nblk + block)*512 + val] -- contiguous 64B stores
        float* sp = s_part + ((size_t)set * gridDim.x + blockIdx.x) * 512;
#pragma unroll
        for (int p = 0; p < PP; p++) {
            float s = ssum[p];
            s += __shfl_xor(s, 16);
            s += __shfl_xor(s, 32);
            if (q == 0) sp[p * 64 + colg] = s;
        }
    } else {
        float* ss = s_sums + set * 512;
#pragma unroll
        for (int p = 0; p < PP; p++) {
            float s = ssum[p];
            s += __shfl_xor(s, 16);
            s += __shfl_xor(s, 32);
            if (q == 0) atomicAdd(&ss[p * 64 + colg], s);
        }
    }
}

// Parallel partial reduce: block (val, set); 256 threads stride through nblk
// block-slots (4B loads 2KB apart -- uncoalesced but 8.4MB total, L2-resident,
// 384 blocks parallel) + LDS tree.
__global__ __launch_bounds__(256) void reduce_ssums(const float* __restrict__ s_part, int nblk,
                                                    float* __restrict__ s_sums) {
    __shared__ float red[256];
    int val = blockIdx.x, set = blockIdx.y;
    const float* sp = s_part + (size_t)set * nblk * 512 + val;
    int t = threadIdx.x;
    float s = 0.f;
    for (int b = t; b < nblk; b += 256) s += sp[(size_t)b * 512];
    red[t] = s;
    __syncthreads();
    for (int off = 128; off > 0; off >>= 1) {
        if (t < off) red[t] += red[t + off];
        __syncthreads();
    }
    if (t == 0) s_sums[set * 512 + val] = red[0];
}

// ---------------- fused kernel B: recompute embed GEMM, mix with beta, write out -----------
// blockIdx.y selects plane-set + beta set + output slice. Pre-split weights.

template <int PP>
__global__ __launch_bounds__(256) void gemm_mix(const short* __restrict__ Xhi0,
                                                const short* __restrict__ Xlo0,
                                                const short* __restrict__ Xhi1,
                                                const short* __restrict__ Xlo1,
                                                const short* __restrict__ Whi_g,
                                                const short* __restrict__ Wlo_g,
                                                const float* __restrict__ b,
                                                const float* __restrict__ a,
                                                const float* __restrict__ beta, int n, int ntiles,
                                                float* __restrict__ outbase, int accum) {
    int set = blockIdx.y;
    const short* __restrict__ Xhi = set ? Xhi1 : Xhi0;
    const short* __restrict__ Xlo = set ? Xlo1 : Xlo0;
    float* __restrict__ out = outbase + (size_t)set * n * 64;
    int t = threadIdx.x;
    int wv = t >> 6, lane = t & 63, nl = lane & 15, q = lane >> 4;
    int colg = wv * 16 + nl;
    bf16x8 whi[PP][2], wlo[PP][2];
    float bias[PP], slope[PP], bet[PP];
#pragma unroll
    for (int p = 0; p < PP; p++) {
#pragma unroll
        for (int kk = 0; kk < 2; kk++) {
            whi[p][kk] = *(const bf16x8*)(Whi_g + p * 4096 + colg * 64 + kk * 32 + q * 8);
            wlo[p][kk] = *(const bf16x8*)(Wlo_g + p * 4096 + colg * 64 + kk * 32 + q * 8);
        }
        bias[p] = b[p * 64 + colg];
        slope[p] = a[p];
        bet[p] = beta[set * 8 + p];
    }
    int rt = blockIdx.x;
    bf16x8 ah[2], al[2];
    if (rt < ntiles) {
        size_t rb = (size_t)(rt * 16 + nl) * 64 + q * 8;
#pragma unroll
        for (int kk = 0; kk < 2; kk++) {
            ah[kk] = *(const bf16x8*)(Xhi + rb + kk * 32);
            al[kk] = *(const bf16x8*)(Xlo + rb + kk * 32);
        }
    }
    for (; rt < ntiles; rt += gridDim.x) {
        int rn = rt + gridDim.x;
        bf16x8 pfh[2], pfl[2];
        if (rn < ntiles) {
            size_t rb = (size_t)(rn * 16 + nl) * 64 + q * 8;
#pragma unroll
            for (int kk = 0; kk < 2; kk++) {
                pfh[kk] = *(const bf16x8*)(Xhi + rb + kk * 32);
                pfl[kk] = *(const bf16x8*)(Xlo + rb + kk * 32);
            }
        }
        float mix[4] = {0.f, 0.f, 0.f, 0.f};
#pragma unroll
        for (int p = 0; p < PP; p++) {
            f32x4 acc = {0.f, 0.f, 0.f, 0.f};
            acc = __builtin_amdgcn_mfma_f32_16x16x32_bf16(ah[0], whi[p][0], acc, 0, 0, 0);
            acc = __builtin_amdgcn_mfma_f32_16x16x32_bf16(ah[1], whi[p][1], acc, 0, 0, 0);
            acc = __builtin_amdgcn_mfma_f32_16x16x32_bf16(al[0], whi[p][0], acc, 0, 0, 0);
            acc = __builtin_amdgcn_mfma_f32_16x16x32_bf16(al[1], whi[p][1], acc, 0, 0, 0);
            acc = __builtin_amdgcn_mfma_f32_16x16x32_bf16(ah[0], wlo[p][0], acc, 0, 0, 0);
            acc = __builtin_amdgcn_mfma_f32_16x16x32_bf16(ah[1], wlo[p][1], acc, 0, 0, 0);
            acc = __builtin_amdgcn_mfma_f32_16x16x32_bf16(al[0], wlo[p][0], acc, 0, 0, 0);
            acc = __builtin_amdgcn_mfma_f32_16x16x32_bf16(al[1], wlo[p][1], acc, 0, 0, 0);
#pragma unroll
            for (int i = 0; i < 4; i++) {
                float o = acc[i] + bias[p];
                o = (o > 0.f) ? o : slope[p] * o;
                mix[i] = fmaf(bet[p], o, mix[i]);
            }
        }
#pragma unroll
        for (int i = 0; i < 4; i++) {
            int r = rt * 16 + q * 4 + i;
            if (r < n) {
                size_t idx = (size_t)r * 64 + colg;
                out[idx] = accum ? (out[idx] + mix[i]) : mix[i];
            }
        }
#pragma unroll
        for (int kk = 0; kk < 2; kk++) {
            ah[kk] = pfh[kk];
            al[kk] = pfl[kk];
        }
    }
}

// beta for nsets plane-sets in one 1-block launch.
__global__ __launch_bounds__(64) void compute_beta(const float* __restrict__ s_sums,
                                                   const float* __restrict__ att, int n, int P,
                                                   int nsets, float* __restrict__ beta) {
    int lane = threadIdx.x;
    float av = att[lane];
    for (int st = 0; st < nsets; st++) {
        const float* ss = s_sums + st * 512;
        float l[8];
        for (int p = 0; p < P; p++) l[p] = ss[p * 64 + lane] * av;
#pragma unroll
        for (int off = 32; off > 0; off >>= 1)
            for (int p = 0; p < 8; p++)
                if (p < P) l[p] += __shfl_down(l[p], off);
        if (lane == 0) {
            const float inv = 1.0f / (float)n;
            float m = -1e30f;
            for (int p = 0; p < P; p++) {
                l[p] *= inv;
                m = fmaxf(m, l[p]);
            }
            float s = 0.f;
            for (int p = 0; p < P; p++) {
                l[p] = __expf(l[p] - m);
                s += l[p];
            }
            for (int p = 0; p < P; p++) beta[st * 8 + p] = l[p] / s;
        }
    }
}

// ---------------- driver ----------------

extern "C" void kernel_launch(void* const* d_in, const int* in_sizes, int n_in,
                              void* d_out, int out_size, void* d_ws, size_t ws_size,
                              hipStream_t stream) {
    const float* h = (const float*)d_in[0];
    const float* W = (const float*)d_in[1];
    const float* b = (const float*)d_in[2];
    const float* a = (const float*)d_in[3];
    const float* fc_w = (const float*)d_in[4];
    const float* fc_b = (const float*)d_in[5];
    const float* att = (const float*)d_in[6];
    const float* adj = (const float*)d_in[7];
    const void* row = d_in[8];
    const void* col = d_in[9];
    const void* mask1 = d_in[10];
    const void* mask2 = d_in[11];
    float* out = (float*)d_out;

    int P = in_sizes[3];
    if (P < 1 || P > 8) P = 3;
    int N = in_sizes[0] / 64;
    int E = in_sizes[7];
    int N16 = (N + 15) & ~15;
    int ntiles = N16 >> 4;

    // bucket geometry: rows/bucket = 1<<shift, buckets <= 2048
    int shift = 8;
    while (((N >> shift) + 1) > 2048) shift++;
    int NB = (N >> shift) + 1;

    char* w = (char*)d_ws;
    auto alloc = [&](size_t bytes) {
        void* p = (void*)w;
        w += (bytes + 255) & ~(size_t)255;
        return p;
    };
    int* row_ptr = (int*)alloc((size_t)(N + 1) * 4);
    int* col_s = (int*)alloc((size_t)E * 4);
    float* val_s = (float*)alloc((size_t)E * 4);
    int* bptr = (int*)alloc((size_t)(NB + 1) * 4);
    int* bcur = (int*)alloc((size_t)NB * 4);
    int2* rcbin = (int2*)alloc((size_t)E * 8);
    float* valbin = (float*)alloc((size_t)E * 4);
    unsigned char* m1c = (unsigned char*)alloc(N);
    unsigned char* m2c = (unsigned char*)alloc(N);
    short* axm_hi = (short*)alloc((size_t)N16 * 64 * 2);
    short* axm_lo = (short*)alloc((size_t)N16 * 64 * 2);
    short* axf_hi = (short*)alloc((size_t)N16 * 64 * 2);
    short* axf_lo = (short*)alloc((size_t)N16 * 64 * 2);
    short* whi_g = (short*)alloc((size_t)8 * 4096 * 2);
    short* wlo_g = (short*)alloc((size_t)8 * 4096 * 2);
    short* fchi_g = (short*)alloc((size_t)4096 * 2);
    short* fclo_g = (short*)alloc((size_t)4096 * 2);
    float* s_sums = (float*)alloc(2 * 512 * 4);
    float* beta = (float*)alloc(64 * 4);
    int* flags = (int*)alloc(256);
    int tanh_blocks = 2048;
    float* s_part = (float*)alloc((size_t)2 * tanh_blocks * 512 * 4);

    int nw_mask = N / 4 > 25000 ? 25000 : N / 4;
    int nw_idx = E / 4 > 25000 ? 25000 : E / 4;
    forensic_kernel<<<1, 256, 0, stream>>>((const unsigned int*)mask1, (const unsigned int*)row,
                                           nw_mask, nw_idx, flags);
    conv_masks<<<(N + 255) / 256, 256, 0, stream>>>(mask1, mask2, flags, N, m1c, m2c);
    int wn = P * 4096, fn = 4096;
    split_weights<<<(wn + fn + 255) / 256, 256, 0, stream>>>(W, fc_w, wn, fn, whi_g, wlo_g,
                                                            fchi_g, fclo_g);

    hipMemsetAsync(bptr, 0, (size_t)(NB + 1) * 4, stream);
    if (N16 > N) {  // zero pad rows so tail-tile fragment loads need no predicate
        size_t padoff = (size_t)N * 64, padbytes = (size_t)(N16 - N) * 64 * 2;
        hipMemsetAsync(axm_hi + padoff, 0, padbytes, stream);
        hipMemsetAsync(axm_lo + padoff, 0, padbytes, stream);
        hipMemsetAsync(axf_hi + padoff, 0, padbytes, stream);
        hipMemsetAsync(axf_lo + padoff, 0, padbytes, stream);
    }
    bucket_hist<<<1024, 256, 0, stream>>>(row, flags, E, N, shift, NB, bptr);
    bucket_scan<<<1, 1024, 0, stream>>>(bptr, NB, bcur, N, row_ptr);
    int bin_blocks = (E + 2047) / 2048;
    bin_pass2<<<bin_blocks, 256, 0, stream>>>(row, col, adj, flags, E, N, shift, NB, bcur, rcbin,
                                              valbin);
    csr_finalize<<<NB, 512, 0, stream>>>(bptr, rcbin, valbin, N, shift, row_ptr, col_s, val_s);

    int spmm_grid = (int)(((size_t)N * 64 + 255) / 256);  // one wave per row
    int mix_blocks = 2048;

    auto tail = [&](const short* xh0, const short* xl0, const short* xh1, const short* xl1,
                    int nsets, float* dst) {
        if (P == 3) {
            gemm_tanh<3><<<dim3(tanh_blocks, nsets), 256, 0, stream>>>(
                xh0, xl0, xh1, xl1, whi_g, wlo_g, b, a, fchi_g, fclo_g, fc_b, N, ntiles, s_sums,
                s_part);
            reduce_ssums<<<dim3(P * 64, nsets), 256, 0, stream>>>(s_part, tanh_blocks, s_sums);
        } else {
            hipMemsetAsync(s_sums, 0, 2 * 512 * 4, stream);
            for (int p = 0; p < P; p++)
                gemm_tanh<1><<<dim3(tanh_blocks, nsets), 256, 0, stream>>>(
                    xh0, xl0, xh1, xl1, whi_g + p * 4096, wlo_g + p * 4096, b + p * 64, a + p,
                    fchi_g, fclo_g, fc_b, N, ntiles, s_sums + p * 64, (float*)nullptr);
        }
        compute_beta<<<1, 64, 0, stream>>>(s_sums, att, N, P, nsets, beta);
        if (P == 3) {
            gemm_mix<3><<<dim3(mix_blocks, nsets), 256, 0, stream>>>(
                xh0, xl0, xh1, xl1, whi_g, wlo_g, b, a, beta, N, ntiles, dst, 0);
        } else {
            for (int p = 0; p < P; p++)
                gemm_mix<1><<<dim3(mix_blocks, nsets), 256, 0, stream>>>(
                    xh0, xl0, xh1, xl1, whi_g + p * 4096, wlo_g + p * 4096, b + p * 64, a + p,
                    beta + p, N, ntiles, dst, p != 0);
        }
    };

    // passes 0+1: one edge sweep -> {axm, axf}; merged tails (gridDim.y = 2)
    spmm_dual<<<spmm_grid, 256, 0, stream>>>(h, row_ptr, col_s, val_s, m1c, N, axm_hi, axm_lo,
                                             axf_hi, axf_lo);
    tail(axm_hi, axm_lo, axf_hi, axf_lo, 2, out);  // z_mp, z_mp2
    // pass 2 decodes from z_mp (in d_out), masked by mask2
    spmm_one<<<spmm_grid, 256, 0, stream>>>(out, row_ptr, col_s, val_s, m2c, N, axm_hi, axm_lo);
    tail(axm_hi, axm_lo, axm_hi, axm_lo, 1, out + (size_t)2 * N * 64);  // x_recon
}

// Round 16
// 562.253 us; speedup vs baseline: 1.0511x; 1.0511x over previous
//
#include <hip/hip_runtime.h>
#include <hip/hip_bf16.h>

typedef __hip_bfloat16 bf16;
typedef __attribute__((ext_vector_type(8))) short bf16x8;  // 8 bf16 in 4 VGPRs
typedef __attribute__((ext_vector_type(4))) float f32x4;

// ---------------- bf16 split helpers (Ootomo bf16x3 scheme) ----------------

__device__ __forceinline__ short f2bf(float x) {  // RNE float->bf16 bits
    unsigned u = __float_as_uint(x);
    unsigned r = (u + 0x7FFFu + ((u >> 16) & 1u)) >> 16;
    return (short)r;
}
__device__ __forceinline__ float bf2f(short s) {
    return __uint_as_float(((unsigned)(unsigned short)s) << 16);
}
__device__ __forceinline__ void split1(float v, short& h, short& l) {
    h = f2bf(v);
    l = f2bf(v - bf2f(h));
}
// Cheap split: RTZ hi (1 shr) + RNE lo. Pair represents v to ~2^-17 rel.
__device__ __forceinline__ void split1_rtz(float v, short& h, short& l) {
    unsigned u = __float_as_uint(v);
    h = (short)(u >> 16);
    float r = v - __uint_as_float(u & 0xFFFF0000u);
    l = f2bf(r);
}

// Load 8 consecutive floats (16B-aligned), split into hi/lo bf16 fragments.
__device__ __forceinline__ void split8(const float* __restrict__ p, bool ok, bf16x8& hi,
                                       bf16x8& lo) {
    float v[8];
    if (ok) {
        float4 x0 = ((const float4*)p)[0];
        float4 x1 = ((const float4*)p)[1];
        v[0] = x0.x; v[1] = x0.y; v[2] = x0.z; v[3] = x0.w;
        v[4] = x1.x; v[5] = x1.y; v[6] = x1.z; v[7] = x1.w;
    } else {
#pragma unroll
        for (int j = 0; j < 8; j++) v[j] = 0.f;
    }
#pragma unroll
    for (int j = 0; j < 8; j++) {
        short hb = f2bf(v[j]);
        hi[j] = hb;
        lo[j] = f2bf(v[j] - bf2f(hb));
    }
}

__device__ __forceinline__ float fast_tanh(float x) {
    x = fminf(fmaxf(x, -15.f), 15.f);
    float t = __expf(2.f * x);
    return __fdividef(t - 1.f, t + 1.f);
}

__device__ __forceinline__ void fma4(float4& acc, float v, const float4& x) {
    acc.x = fmaf(v, x.x, acc.x);
    acc.y = fmaf(v, x.y, acc.y);
    acc.z = fmaf(v, x.z, acc.z);
    acc.w = fmaf(v, x.w, acc.w);
}

__device__ __forceinline__ void red4(float4& a) {
    a.x += __shfl_xor(a.x, 16); a.y += __shfl_xor(a.y, 16);
    a.z += __shfl_xor(a.z, 16); a.w += __shfl_xor(a.w, 16);
    a.x += __shfl_xor(a.x, 32); a.y += __shfl_xor(a.y, 32);
    a.z += __shfl_xor(a.z, 32); a.w += __shfl_xor(a.w, 32);
}

// ---------------- dtype forensics (masks / indices) ----------------
// modes: 0=u8/bool, 1=int32, 2=float32, 3=int64, 4=float64
__global__ __launch_bounds__(256) void forensic_kernel(const unsigned int* __restrict__ mask_w,
                                                       const unsigned int* __restrict__ idx_w,
                                                       int nw_mask, int nw_idx,
                                                       int* __restrict__ flags) {
    __shared__ int sm[6];
    int t = threadIdx.x;
    if (t < 6) sm[t] = 0;
    __syncthreads();
    int m_gt1 = 0, m_f32 = 0, m_f64 = 0, m_oddnz = 0, i_hi = 0, i_oddnz = 0;
    for (int i = t; i < nw_mask; i += 256) {
        unsigned int w = mask_w[i];
        if (w > 1u && w != 0x3F800000u && w != 0x3FF00000u) m_gt1++;
        if (w == 0x3F800000u) m_f32++;
        if ((i & 1) && w == 0x3FF00000u) m_f64++;
        if ((i & 1) && w != 0u) m_oddnz++;
    }
    for (int i = t; i < nw_idx; i += 256) {
        unsigned int v = idx_w[i];
        if (v >= 0x20000000u) i_hi++;
        if ((i & 1) && v != 0u) i_oddnz++;
    }
    atomicAdd(&sm[0], m_gt1);
    atomicAdd(&sm[1], m_f32);
    atomicAdd(&sm[2], m_f64);
    atomicAdd(&sm[3], m_oddnz);
    atomicAdd(&sm[4], i_hi);
    atomicAdd(&sm[5], i_oddnz);
    __syncthreads();
    if (t == 0) {
        int mmode;
        if (sm[1] > 50) mmode = 2;
        else if (sm[2] > 50) mmode = 4;
        else if (sm[0] > 50) mmode = 0;
        else if (sm[3] > 50) mmode = 1;
        else mmode = 3;
        int imode;
        if (sm[4] > (nw_idx * 3) / 4) imode = 2;
        else if (sm[4] > nw_idx / 4) imode = 4;
        else if (sm[5] > 50) imode = 1;
        else imode = 3;
        flags[0] = mmode;
        flags[1] = imode;
    }
}

__device__ __forceinline__ int fetch_idx(const void* p, int e, int mode) {
    switch (mode) {
        case 1: return ((const int*)p)[e];
        case 3: return (int)(((const long long*)p)[e]);
        case 2: return (int)(((const float*)p)[e]);
        default: return (int)(((const double*)p)[e]);
    }
}

__device__ __forceinline__ bool conv_one(const void* m, int mode, int i) {
    switch (mode) {
        case 0: return ((const unsigned char*)m)[i] != 0;
        case 1: return ((const int*)m)[i] != 0;
        case 2: return ((const float*)m)[i] != 0.f;
        case 3: return ((const long long*)m)[i] != 0;
        default: return ((const double*)m)[i] != 0.0;
    }
}

// Both masks in one launch.
__global__ __launch_bounds__(256) void conv_masks(const void* __restrict__ m1,
                                                  const void* __restrict__ m2,
                                                  const int* __restrict__ flags, int n,
                                                  unsigned char* __restrict__ o1,
                                                  unsigned char* __restrict__ o2) {
    int mode = flags[0];
    int i = blockIdx.x * 256 + threadIdx.x;
    if (i >= n) return;
    o1[i] = conv_one(m1, mode, i) ? 1 : 0;
    o2[i] = conv_one(m2, mode, i) ? 1 : 0;
}

// ---------------- CSR build: two-level bucket sort, block-aggregated binning --------

__global__ __launch_bounds__(256) void bucket_hist(const void* __restrict__ row,
                                                   const int* __restrict__ flags, int e_cnt,
                                                   int n, int shift, int nb,
                                                   int* __restrict__ bcnt) {
    __shared__ int hist[2048];
    int t = threadIdx.x;
    for (int i = t; i < nb; i += 256) hist[i] = 0;
    __syncthreads();
    int imode = flags[1];
    for (int e = blockIdx.x * 256 + t; e < e_cnt; e += gridDim.x * 256) {
        int r = fetch_idx(row, e, imode);
        if ((unsigned)r < (unsigned)n) atomicAdd(&hist[r >> shift], 1);
    }
    __syncthreads();
    for (int i = t; i < nb; i += 256)
        if (hist[i]) atomicAdd(&bcnt[i], hist[i]);
}

// bptr: in = counts, out = exclusive offsets; also fills bcur and row_ptr[n].
__global__ __launch_bounds__(1024) void bucket_scan(int* __restrict__ bptr, int nb,
                                                    int* __restrict__ bcur, int n,
                                                    int* __restrict__ row_ptr) {
    __shared__ int sh[1024];
    int t = threadIdx.x;
    int i0 = t * 2, i1 = t * 2 + 1;
    int a = (i0 < nb) ? bptr[i0] : 0;
    int b = (i1 < nb) ? bptr[i1] : 0;
    int s = a + b;
    sh[t] = s;
    __syncthreads();
    for (int off = 1; off < 1024; off <<= 1) {
        int u = (t >= off) ? sh[t - off] : 0;
        __syncthreads();
        sh[t] += u;
        __syncthreads();
    }
    int base = sh[t] - s;  // exclusive prefix
    if (i0 < nb) { bptr[i0] = base; bcur[i0] = base; }
    if (i1 < nb) { bptr[i1] = base + a; bcur[i1] = base + a; }
    if (t == 1023) {
        bptr[nb] = sh[1023];
        row_ptr[n] = sh[1023];
    }
}

// Block-aggregated binning; 2048 edges/block, register-cached.
__global__ __launch_bounds__(256) void bin_pass2(const void* __restrict__ row,
                                                 const void* __restrict__ col,
                                                 const float* __restrict__ vals,
                                                 const int* __restrict__ flags, int e_cnt, int n,
                                                 int shift, int nb, int* __restrict__ bcur,
                                                 int2* __restrict__ rcbin,
                                                 float* __restrict__ valbin) {
    __shared__ int hist[2048];
    __shared__ int base[2048];
    int t = threadIdx.x;
    int e0 = blockIdx.x * 2048;
    if (e0 >= e_cnt) return;
    int imode = flags[1];
    for (int i = t; i < nb; i += 256) hist[i] = 0;
    __syncthreads();
    // phase 1: load this thread's 8 edges into registers + LDS histogram
    int rr[8], cc[8];
    float vv[8];
    bool ok[8];
#pragma unroll
    for (int j = 0; j < 8; j++) {
        int e = e0 + j * 256 + t;
        ok[j] = false;
        if (e < e_cnt) {
            int r = fetch_idx(row, e, imode);
            if ((unsigned)r < (unsigned)n) {
                ok[j] = true;
                rr[j] = r;
                int c = fetch_idx(col, e, imode);
                cc[j] = ((unsigned)c < (unsigned)n) ? c : 0;
                vv[j] = vals[e];
                atomicAdd(&hist[r >> shift], 1);
            }
        }
    }
    __syncthreads();
    // phase 2: reserve one contiguous range per bucket (1 global atomic each)
    for (int i = t; i < nb; i += 256) {
        int c = hist[i];
        base[i] = c ? atomicAdd(&bcur[i], c) : 0;
        hist[i] = 0;  // reuse as within-block cursor
    }
    __syncthreads();
    // phase 3: scatter from registers into reserved ranges
#pragma unroll
    for (int j = 0; j < 8; j++) {
        if (ok[j]) {
            int bk = rr[j] >> shift;
            int pos = base[bk] + atomicAdd(&hist[bk], 1);
            rcbin[pos] = make_int2(rr[j], cc[j]);
            valbin[pos] = vv[j];
        }
    }
}

// One block per bucket, 512 threads. rows-per-bucket <= 1024.
__global__ __launch_bounds__(512) void csr_finalize(const int* __restrict__ bptr,
                                                    const int2* __restrict__ rcbin,
                                                    const float* __restrict__ valbin, int n,
                                                    int shift, int* __restrict__ row_ptr,
                                                    int* __restrict__ col_s,
                                                    float* __restrict__ val_s) {
    __shared__ int cnt[1024];
    __shared__ int curs[1024];
    __shared__ int red[512];
    int b = blockIdx.x, t = threadIdx.x;
    int rpb = 1 << shift;
    int r0 = b << shift;
    int rows = n - r0;
    if (rows <= 0) return;
    if (rows > rpb) rows = rpb;
    int ebase = bptr[b], eend = bptr[b + 1];
    for (int i = t; i < rows; i += 512) cnt[i] = 0;
    __syncthreads();
    for (int e = ebase + t; e < eend; e += 512) atomicAdd(&cnt[rcbin[e].x - r0], 1);
    __syncthreads();
    // exclusive scan of cnt[0..rows): 2 values per thread + block scan
    int v[2], s = 0;
#pragma unroll
    for (int j = 0; j < 2; j++) {
        int idx = t * 2 + j;
        v[j] = (idx < rows) ? cnt[idx] : 0;
        s += v[j];
    }
    red[t] = s;
    __syncthreads();
    for (int off = 1; off < 512; off <<= 1) {
        int u = (t >= off) ? red[t - off] : 0;
        __syncthreads();
        red[t] += u;
        __syncthreads();
    }
    int run = ebase + red[t] - s;
#pragma unroll
    for (int j = 0; j < 2; j++) {
        int idx = t * 2 + j;
        if (idx < rows) {
            row_ptr[r0 + idx] = run;
            curs[idx] = run;
            run += v[j];
        }
    }
    __syncthreads();
    for (int e = ebase + t; e < eend; e += 512) {
        int2 rc = rcbin[e];
        float vv = valbin[e];
        int pos = atomicAdd(&curs[rc.x - r0], 1);
        col_s[pos] = rc.y;
        val_s[pos] = vv;
    }
}

// ---------------- SpMM: ax = A @ x  (CSR, one wave per row) ----------------
// One row/wave, 4-deep gather unroll (measured best, rounds 7/9). Outputs are
// pre-split bf16 hi/lo planes.

__device__ __forceinline__ void store_split4(short* __restrict__ hi, short* __restrict__ lo,
                                             size_t o, const float4& v) {
    short4 h4, l4;
    split1(v.x, h4.x, l4.x); split1(v.y, h4.y, l4.y);
    split1(v.z, h4.z, l4.z); split1(v.w, h4.w, l4.w);
    *(short4*)(hi + o) = h4;
    *(short4*)(lo + o) = l4;
}

__global__ __launch_bounds__(256) void spmm_dual(const float* __restrict__ X,
                                                 const int* __restrict__ row_ptr,
                                                 const int* __restrict__ col_s,
                                                 const float* __restrict__ val_s,
                                                 const unsigned char* __restrict__ mask, int n,
                                                 short* __restrict__ axm_hi,
                                                 short* __restrict__ axm_lo,
                                                 short* __restrict__ axf_hi,
                                                 short* __restrict__ axf_lo) {
    int gid = blockIdx.x * 256 + threadIdx.x;
    int r = gid >> 6;
    if (r >= n) return;
    int lane = threadIdx.x & 63;
    int g = lane >> 4, sub = lane & 15;
    int s = row_ptr[r], e = row_ptr[r + 1];
    int cnt = e - s;
    int myc = 0;
    float myvf = 0.f, myvm = 0.f;
    if (lane < cnt) {
        myc = col_s[s + lane];
        float v = val_s[s + lane];
        myvf = v;
        myvm = mask[myc] ? 0.f : v;
    }
    int cmain = cnt > 64 ? 64 : cnt;
    float4 fA = {0, 0, 0, 0}, fB = {0, 0, 0, 0}, mA = {0, 0, 0, 0}, mB = {0, 0, 0, 0};
    for (int i = 0; i < cmain; i += 16) {
        int i0 = i + g, i1 = i + 4 + g, i2 = i + 8 + g, i3 = i + 12 + g;
        int c0 = __shfl(myc, i0), c1 = __shfl(myc, i1);
        int c2 = __shfl(myc, i2), c3 = __shfl(myc, i3);
        float vf0 = __shfl(myvf, i0), vf1 = __shfl(myvf, i1);
        float vf2 = __shfl(myvf, i2), vf3 = __shfl(myvf, i3);
        float vm0 = __shfl(myvm, i0), vm1 = __shfl(myvm, i1);
        float vm2 = __shfl(myvm, i2), vm3 = __shfl(myvm, i3);
        if (i0 < cmain) {
            float4 x = *(const float4*)(X + (size_t)c0 * 64 + sub * 4);
            fma4(fA, vf0, x);
            fma4(mA, vm0, x);
        }
        if (i1 < cmain) {
            float4 x = *(const float4*)(X + (size_t)c1 * 64 + sub * 4);
            fma4(fB, vf1, x);
            fma4(mB, vm1, x);
        }
        if (i2 < cmain) {
            float4 x = *(const float4*)(X + (size_t)c2 * 64 + sub * 4);
            fma4(fA, vf2, x);
            fma4(mA, vm2, x);
        }
        if (i3 < cmain) {
            float4 x = *(const float4*)(X + (size_t)c3 * 64 + sub * 4);
            fma4(fB, vf3, x);
            fma4(mB, vm3, x);
        }
    }
    for (int i = 64 + g; i < cnt; i += 4) {  // rare overflow rows
        int c = col_s[s + i];
        float v = val_s[s + i];
        float vm = mask[c] ? 0.f : v;
        float4 x = *(const float4*)(X + (size_t)c * 64 + sub * 4);
        fma4(fA, v, x);
        fma4(mA, vm, x);
    }
    fA.x += fB.x; fA.y += fB.y; fA.z += fB.z; fA.w += fB.w;
    mA.x += mB.x; mA.y += mB.y; mA.z += mB.z; mA.w += mB.w;
    red4(fA);
    red4(mA);
    if (g == 0) {
        size_t o = (size_t)r * 64 + sub * 4;
        store_split4(axf_hi, axf_lo, o, fA);
        store_split4(axm_hi, axm_lo, o, mA);
    }
}

// Single-output masked SpMM; masked edges skip the gather entirely.
__global__ __launch_bounds__(256) void spmm_one(const float* __restrict__ X,
                                                const int* __restrict__ row_ptr,
                                                const int* __restrict__ col_s,
                                                const float* __restrict__ val_s,
                                                const unsigned char* __restrict__ mask, int n,
                                                short* __restrict__ ax_hi,
                                                short* __restrict__ ax_lo) {
    int gid = blockIdx.x * 256 + threadIdx.x;
    int r = gid >> 6;
    if (r >= n) return;
    int lane = threadIdx.x & 63;
    int g = lane >> 4, sub = lane & 15;
    int s = row_ptr[r], e = row_ptr[r + 1];
    int cnt = e - s;
    int myc = 0;
    float myv = 0.f;
    if (lane < cnt) {
        myc = col_s[s + lane];
        float v = val_s[s + lane];
        myv = mask[myc] ? 0.f : v;
    }
    int cmain = cnt > 64 ? 64 : cnt;
    float4 aA = {0, 0, 0, 0}, aB = {0, 0, 0, 0};
    for (int i = 0; i < cmain; i += 16) {
        int i0 = i + g, i1 = i + 4 + g, i2 = i + 8 + g, i3 = i + 12 + g;
        int c0 = __shfl(myc, i0), c1 = __shfl(myc, i1);
        int c2 = __shfl(myc, i2), c3 = __shfl(myc, i3);
        float v0 = __shfl(myv, i0), v1 = __shfl(myv, i1);
        float v2 = __shfl(myv, i2), v3 = __shfl(myv, i3);
        if (i0 < cmain && v0 != 0.f) {
            float4 x = *(const float4*)(X + (size_t)c0 * 64 + sub * 4);
            fma4(aA, v0, x);
        }
        if (i1 < cmain && v1 != 0.f) {
            float4 x = *(const float4*)(X + (size_t)c1 * 64 + sub * 4);
            fma4(aB, v1, x);
        }
        if (i2 < cmain && v2 != 0.f) {
            float4 x = *(const float4*)(X + (size_t)c2 * 64 + sub * 4);
            fma4(aA, v2, x);
        }
        if (i3 < cmain && v3 != 0.f) {
            float4 x = *(const float4*)(X + (size_t)c3 * 64 + sub * 4);
            fma4(aB, v3, x);
        }
    }
    for (int i = 64 + g; i < cnt; i += 4) {
        int c = col_s[s + i];
        if (mask[c]) continue;
        float v = val_s[s + i];
        float4 x = *(const float4*)(X + (size_t)c * 64 + sub * 4);
        fma4(aA, v, x);
    }
    aA.x += aB.x; aA.y += aB.y; aA.z += aB.z; aA.w += aB.w;
    red4(aA);
    if (g == 0) {
        size_t o = (size_t)r * 64 + sub * 4;
        store_split4(ax_hi, ax_lo, o, aA);
    }
}

// ---------------- fused kernel A: embed GEMM -> LDS bf16 planes -> fc GEMM -> tanh-sum ----
// Measured-best config (round 9, 561us): per-block split8 weight prologue,
// atomicAdd s_sums, grid 1024. blockIdx.y selects plane-set {0,1}.

template <int PP>
__global__ __launch_bounds__(256) void gemm_tanh(const short* __restrict__ Xhi0,
                                                 const short* __restrict__ Xlo0,
                                                 const short* __restrict__ Xhi1,
                                                 const short* __restrict__ Xlo1,
                                                 const float* __restrict__ Wg,
                                                 const float* __restrict__ b,
                                                 const float* __restrict__ a,
                                                 const float* __restrict__ fcw,
                                                 const float* __restrict__ fcb, int n, int ntiles,
                                                 float* __restrict__ s_sums) {
    __shared__ __align__(16) short ehi[PP][16][72], elo[PP][16][72];
    int set = blockIdx.y;
    const short* __restrict__ Xhi = set ? Xhi1 : Xhi0;
    const short* __restrict__ Xlo = set ? Xlo1 : Xlo0;
    float* __restrict__ ss = s_sums + set * 512;
    int t = threadIdx.x;
    int wv = t >> 6, lane = t & 63, nl = lane & 15, q = lane >> 4;
    int colg = wv * 16 + nl;
    bf16x8 whi[PP][2], wlo[PP][2];
    float bias[PP], slope[PP];
#pragma unroll
    for (int p = 0; p < PP; p++) {
#pragma unroll
        for (int kk = 0; kk < 2; kk++)
            split8(Wg + p * 4096 + colg * 64 + kk * 32 + q * 8, true, whi[p][kk], wlo[p][kk]);
        bias[p] = b[p * 64 + colg];
        slope[p] = a[p];
    }
    bf16x8 fhi[2], flo[2];
#pragma unroll
    for (int kk = 0; kk < 2; kk++)
        split8(fcw + colg * 64 + kk * 32 + q * 8, true, fhi[kk], flo[kk]);
    float fbias = fcb[colg];
    float ssum[PP];
#pragma unroll
    for (int p = 0; p < PP; p++) ssum[p] = 0.f;

    int rt = blockIdx.x;
    bf16x8 ah[2], al[2];
    if (rt < ntiles) {
        size_t rb = (size_t)(rt * 16 + nl) * 64 + q * 8;
#pragma unroll
        for (int kk = 0; kk < 2; kk++) {
            ah[kk] = *(const bf16x8*)(Xhi + rb + kk * 32);
            al[kk] = *(const bf16x8*)(Xlo + rb + kk * 32);
        }
    }
    for (; rt < ntiles; rt += gridDim.x) {
#pragma unroll
        for (int p = 0; p < PP; p++) {
            f32x4 acc = {0.f, 0.f, 0.f, 0.f};
            acc = __builtin_amdgcn_mfma_f32_16x16x32_bf16(ah[0], whi[p][0], acc, 0, 0, 0);
            acc = __builtin_amdgcn_mfma_f32_16x16x32_bf16(ah[1], whi[p][1], acc, 0, 0, 0);
            acc = __builtin_amdgcn_mfma_f32_16x16x32_bf16(al[0], whi[p][0], acc, 0, 0, 0);
            acc = __builtin_amdgcn_mfma_f32_16x16x32_bf16(al[1], whi[p][1], acc, 0, 0, 0);
            acc = __builtin_amdgcn_mfma_f32_16x16x32_bf16(ah[0], wlo[p][0], acc, 0, 0, 0);
            acc = __builtin_amdgcn_mfma_f32_16x16x32_bf16(ah[1], wlo[p][1], acc, 0, 0, 0);
            acc = __builtin_amdgcn_mfma_f32_16x16x32_bf16(al[0], wlo[p][0], acc, 0, 0, 0);
            acc = __builtin_amdgcn_mfma_f32_16x16x32_bf16(al[1], wlo[p][1], acc, 0, 0, 0);
#pragma unroll
            for (int i = 0; i < 4; i++) {
                float o = acc[i] + bias[p];
                o = (o > 0.f) ? o : slope[p] * o;
                short hb, lb;
                split1_rtz(o, hb, lb);
                ehi[p][q * 4 + i][colg] = hb;
                elo[p][q * 4 + i][colg] = lb;
            }
        }
        // prefetch next tile's A-fragments (overlaps the fc phase below)
        int rn = rt + gridDim.x;
        bf16x8 pfh[2], pfl[2];
        if (rn < ntiles) {
            size_t rb = (size_t)(rn * 16 + nl) * 64 + q * 8;
#pragma unroll
            for (int kk = 0; kk < 2; kk++) {
                pfh[kk] = *(const bf16x8*)(Xhi + rb + kk * 32);
                pfl[kk] = *(const bf16x8*)(Xlo + rb + kk * 32);
            }
        }
        __syncthreads();
#pragma unroll
        for (int p = 0; p < PP; p++) {
            bf16x8 eh[2], el[2];
#pragma unroll
            for (int kk = 0; kk < 2; kk++) {
                eh[kk] = *(const bf16x8*)(&ehi[p][nl][kk * 32 + q * 8]);
                el[kk] = *(const bf16x8*)(&elo[p][nl][kk * 32 + q * 8]);
            }
            f32x4 acc = {0.f, 0.f, 0.f, 0.f};
            acc = __builtin_amdgcn_mfma_f32_16x16x32_bf16(eh[0], fhi[0], acc, 0, 0, 0);
            acc = __builtin_amdgcn_mfma_f32_16x16x32_bf16(eh[1], fhi[1], acc, 0, 0, 0);
            acc = __builtin_amdgcn_mfma_f32_16x16x32_bf16(el[0], fhi[0], acc, 0, 0, 0);
            acc = __builtin_amdgcn_mfma_f32_16x16x32_bf16(el[1], fhi[1], acc, 0, 0, 0);
            acc = __builtin_amdgcn_mfma_f32_16x16x32_bf16(eh[0], flo[0], acc, 0, 0, 0);
            acc = __builtin_amdgcn_mfma_f32_16x16x32_bf16(eh[1], flo[1], acc, 0, 0, 0);
#pragma unroll
            for (int i = 0; i < 4; i++) {
                int r = rt * 16 + q * 4 + i;
                if (r < n) ssum[p] += fast_tanh(acc[i] + fbias);
            }
        }
        __syncthreads();  // LDS reads done before next tile's writes
#pragma unroll
        for (int kk = 0; kk < 2; kk++) {
            ah[kk] = pfh[kk];
            al[kk] = pfl[kk];
        }
    }
#pragma unroll
    for (int p = 0; p < PP; p++) {
        float s = ssum[p];
        s += __shfl_xor(s, 16);
        s += __shfl_xor(s, 32);
        if (q == 0) atomicAdd(&ss[p * 64 + colg], s);
    }
}

// ---------------- fused kernel B: recompute embed GEMM, mix with beta, write out -----------
// blockIdx.y selects plane-set + beta set + output slice.

template <int PP>
__global__ __launch_bounds__(256) void gemm_mix(const short* __restrict__ Xhi0,
                                                const short* __restrict__ Xlo0,
                                                const short* __restrict__ Xhi1,
                                                const short* __restrict__ Xlo1,
                                                const float* __restrict__ Wg,
                                                const float* __restrict__ b,
                                                const float* __restrict__ a,
                                                const float* __restrict__ beta, int n, int ntiles,
                                                float* __restrict__ outbase, int accum) {
    int set = blockIdx.y;
    const short* __restrict__ Xhi = set ? Xhi1 : Xhi0;
    const short* __restrict__ Xlo = set ? Xlo1 : Xlo0;
    float* __restrict__ out = outbase + (size_t)set * n * 64;
    int t = threadIdx.x;
    int wv = t >> 6, lane = t & 63, nl = lane & 15, q = lane >> 4;
    int colg = wv * 16 + nl;
    bf16x8 whi[PP][2], wlo[PP][2];
    float bias[PP], slope[PP], bet[PP];
#pragma unroll
    for (int p = 0; p < PP; p++) {
#pragma unroll
        for (int kk = 0; kk < 2; kk++)
            split8(Wg + p * 4096 + colg * 64 + kk * 32 + q * 8, true, whi[p][kk], wlo[p][kk]);
        bias[p] = b[p * 64 + colg];
        slope[p] = a[p];
        bet[p] = beta[set * 8 + p];
    }
    int rt = blockIdx.x;
    bf16x8 ah[2], al[2];
    if (rt < ntiles) {
        size_t rb = (size_t)(rt * 16 + nl) * 64 + q * 8;
#pragma unroll
        for (int kk = 0; kk < 2; kk++) {
            ah[kk] = *(const bf16x8*)(Xhi + rb + kk * 32);
            al[kk] = *(const bf16x8*)(Xlo + rb + kk * 32);
        }
    }
    for (; rt < ntiles; rt += gridDim.x) {
        int rn = rt + gridDim.x;
        bf16x8 pfh[2], pfl[2];
        if (rn < ntiles) {
            size_t rb = (size_t)(rn * 16 + nl) * 64 + q * 8;
#pragma unroll
            for (int kk = 0; kk < 2; kk++) {
                pfh[kk] = *(const bf16x8*)(Xhi + rb + kk * 32);
                pfl[kk] = *(const bf16x8*)(Xlo + rb + kk * 32);
            }
        }
        float mix[4] = {0.f, 0.f, 0.f, 0.f};
#pragma unroll
        for (int p = 0; p < PP; p++) {
            f32x4 acc = {0.f, 0.f, 0.f, 0.f};
            acc = __builtin_amdgcn_mfma_f32_16x16x32_bf16(ah[0], whi[p][0], acc, 0, 0, 0);
            acc = __builtin_amdgcn_mfma_f32_16x16x32_bf16(ah[1], whi[p][1], acc, 0, 0, 0);
            acc = __builtin_amdgcn_mfma_f32_16x16x32_bf16(al[0], whi[p][0], acc, 0, 0, 0);
            acc = __builtin_amdgcn_mfma_f32_16x16x32_bf16(al[1], whi[p][1], acc, 0, 0, 0);
            acc = __builtin_amdgcn_mfma_f32_16x16x32_bf16(ah[0], wlo[p][0], acc, 0, 0, 0);
            acc = __builtin_amdgcn_mfma_f32_16x16x32_bf16(ah[1], wlo[p][1], acc, 0, 0, 0);
            acc = __builtin_amdgcn_mfma_f32_16x16x32_bf16(al[0], wlo[p][0], acc, 0, 0, 0);
            acc = __builtin_amdgcn_mfma_f32_16x16x32_bf16(al[1], wlo[p][1], acc, 0, 0, 0);
#pragma unroll
            for (int i = 0; i < 4; i++) {
                float o = acc[i] + bias[p];
                o = (o > 0.f) ? o : slope[p] * o;
                mix[i] = fmaf(bet[p], o, mix[i]);
            }
        }
#pragma unroll
        for (int i = 0; i < 4; i++) {
            int r = rt * 16 + q * 4 + i;
            if (r < n) {
                size_t idx = (size_t)r * 64 + colg;
                out[idx] = accum ? (out[idx] + mix[i]) : mix[i];
            }
        }
#pragma unroll
        for (int kk = 0; kk < 2; kk++) {
            ah[kk] = pfh[kk];
            al[kk] = pfl[kk];
        }
    }
}

// beta for nsets plane-sets in one 1-block launch.
__global__ __launch_bounds__(64) void compute_beta(const float* __restrict__ s_sums,
                                                   const float* __restrict__ att, int n, int P,
                                                   int nsets, float* __restrict__ beta) {
    int lane = threadIdx.x;
    float av = att[lane];
    for (int st = 0; st < nsets; st++) {
        const float* ss = s_sums + st * 512;
        float l[8];
        for (int p = 0; p < P; p++) l[p] = ss[p * 64 + lane] * av;
#pragma unroll
        for (int off = 32; off > 0; off >>= 1)
            for (int p = 0; p < 8; p++)
                if (p < P) l[p] += __shfl_down(l[p], off);
        if (lane == 0) {
            const float inv = 1.0f / (float)n;
            float m = -1e30f;
            for (int p = 0; p < P; p++) {
                l[p] *= inv;
                m = fmaxf(m, l[p]);
            }
            float s = 0.f;
            for (int p = 0; p < P; p++) {
                l[p] = __expf(l[p] - m);
                s += l[p];
            }
            for (int p = 0; p < P; p++) beta[st * 8 + p] = l[p] / s;
        }
    }
}

// ---------------- driver ----------------

extern "C" void kernel_launch(void* const* d_in, const int* in_sizes, int n_in,
                              void* d_out, int out_size, void* d_ws, size_t ws_size,
                              hipStream_t stream) {
    const float* h = (const float*)d_in[0];
    const float* W = (const float*)d_in[1];
    const float* b = (const float*)d_in[2];
    const float* a = (const float*)d_in[3];
    const float* fc_w = (const float*)d_in[4];
    const float* fc_b = (const float*)d_in[5];
    const float* att = (const float*)d_in[6];
    const float* adj = (const float*)d_in[7];
    const void* row = d_in[8];
    const void* col = d_in[9];
    const void* mask1 = d_in[10];
    const void* mask2 = d_in[11];
    float* out = (float*)d_out;

    int P = in_sizes[3];
    if (P < 1 || P > 8) P = 3;
    int N = in_sizes[0] / 64;
    int E = in_sizes[7];
    int N16 = (N + 15) & ~15;
    int ntiles = N16 >> 4;

    // bucket geometry: rows/bucket = 1<<shift, buckets <= 2048
    int shift = 8;
    while (((N >> shift) + 1) > 2048) shift++;
    int NB = (N >> shift) + 1;

    char* w = (char*)d_ws;
    auto alloc = [&](size_t bytes) {
        void* p = (void*)w;
        w += (bytes + 255) & ~(size_t)255;
        return p;
    };
    int* row_ptr = (int*)alloc((size_t)(N + 1) * 4);
    int* col_s = (int*)alloc((size_t)E * 4);
    float* val_s = (float*)alloc((size_t)E * 4);
    int* bptr = (int*)alloc((size_t)(NB + 1) * 4);
    int* bcur = (int*)alloc((size_t)NB * 4);
    int2* rcbin = (int2*)alloc((size_t)E * 8);
    float* valbin = (float*)alloc((size_t)E * 4);
    unsigned char* m1c = (unsigned char*)alloc(N);
    unsigned char* m2c = (unsigned char*)alloc(N);
    short* axm_hi = (short*)alloc((size_t)N16 * 64 * 2);
    short* axm_lo = (short*)alloc((size_t)N16 * 64 * 2);
    short* axf_hi = (short*)alloc((size_t)N16 * 64 * 2);
    short* axf_lo = (short*)alloc((size_t)N16 * 64 * 2);
    float* s_sums = (float*)alloc(2 * 512 * 4);
    float* beta = (float*)alloc(64 * 4);
    int* flags = (int*)alloc(256);

    int nw_mask = N / 4 > 25000 ? 25000 : N / 4;
    int nw_idx = E / 4 > 25000 ? 25000 : E / 4;
    forensic_kernel<<<1, 256, 0, stream>>>((const unsigned int*)mask1, (const unsigned int*)row,
                                           nw_mask, nw_idx, flags);
    conv_masks<<<(N + 255) / 256, 256, 0, stream>>>(mask1, mask2, flags, N, m1c, m2c);

    hipMemsetAsync(bptr, 0, (size_t)(NB + 1) * 4, stream);
    if (N16 > N) {  // zero pad rows so tail-tile fragment loads need no predicate
        size_t padoff = (size_t)N * 64, padbytes = (size_t)(N16 - N) * 64 * 2;
        hipMemsetAsync(axm_hi + padoff, 0, padbytes, stream);
        hipMemsetAsync(axm_lo + padoff, 0, padbytes, stream);
        hipMemsetAsync(axf_hi + padoff, 0, padbytes, stream);
        hipMemsetAsync(axf_lo + padoff, 0, padbytes, stream);
    }
    bucket_hist<<<1024, 256, 0, stream>>>(row, flags, E, N, shift, NB, bptr);
    bucket_scan<<<1, 1024, 0, stream>>>(bptr, NB, bcur, N, row_ptr);
    int bin_blocks = (E + 2047) / 2048;
    bin_pass2<<<bin_blocks, 256, 0, stream>>>(row, col, adj, flags, E, N, shift, NB, bcur, rcbin,
                                              valbin);
    csr_finalize<<<NB, 512, 0, stream>>>(bptr, rcbin, valbin, N, shift, row_ptr, col_s, val_s);

    int spmm_grid = (int)(((size_t)N * 64 + 255) / 256);  // one wave per row
    int tanh_blocks = 1024;
    int mix_blocks = 1024;

    auto tail = [&](const short* xh0, const short* xl0, const short* xh1, const short* xl1,
                    int nsets, float* dst) {
        hipMemsetAsync(s_sums, 0, 2 * 512 * 4, stream);
        if (P == 3) {
            gemm_tanh<3><<<dim3(tanh_blocks, nsets), 256, 0, stream>>>(
                xh0, xl0, xh1, xl1, W, b, a, fc_w, fc_b, N, ntiles, s_sums);
        } else {
            for (int p = 0; p < P; p++)
                gemm_tanh<1><<<dim3(tanh_blocks, nsets), 256, 0, stream>>>(
                    xh0, xl0, xh1, xl1, W + p * 4096, b + p * 64, a + p, fc_w, fc_b, N, ntiles,
                    s_sums + p * 64);
        }
        compute_beta<<<1, 64, 0, stream>>>(s_sums, att, N, P, nsets, beta);
        if (P == 3) {
            gemm_mix<3><<<dim3(mix_blocks, nsets), 256, 0, stream>>>(
                xh0, xl0, xh1, xl1, W, b, a, beta, N, ntiles, dst, 0);
        } else {
            for (int p = 0; p < P; p++)
                gemm_mix<1><<<dim3(mix_blocks, nsets), 256, 0, stream>>>(
                    xh0, xl0, xh1, xl1, W + p * 4096, b + p * 64, a + p, beta + p, N, ntiles, dst,
                    p != 0);
        }
    };

    // passes 0+1: one edge sweep -> {axm, axf}; merged tails (gridDim.y = 2)
    spmm_dual<<<spmm_grid, 256, 0, stream>>>(h, row_ptr, col_s, val_s, m1c, N, axm_hi, axm_lo,
                                             axf_hi, axf_lo);
    tail(axm_hi, axm_lo, axf_hi, axf_lo, 2, out);  // z_mp, z_mp2
    // pass 2 decodes from z_mp (in d_out), masked by mask2
    spmm_one<<<spmm_grid, 256, 0, stream>>>(out, row_ptr, col_s, val_s, m2c, N, axm_hi, axm_lo);
    tail(axm_hi, axm_lo, axm_hi, axm_lo, 1, out + (size_t)2 * N * 64);  // x_recon
}